// Round 8
// baseline (710.939 us; speedup 1.0000x reference)
//
#include <hip/hip_runtime.h>

#define SS 384
#define BB 2
#define DD 256
#define NPART 1024
#define REPS 5

typedef float f32x4 __attribute__((ext_vector_type(4)));

// ws float layout:
//  [16..16+1024)  W partial sums
//  [2048..2816)   m1 row sums  (b*S+i)
//  [2816..3584)   m2 row sums
//  [3584..4352)   m3 row sums (raw)
#define WS_PART 16
#define WS_M1 2048
#define WS_M2 2816
#define WS_M3 3584

// --- fused stage 1: blocks [0,NPART) do W partial sums; blocks [NPART, NPART+576) do row sums
__global__ void stage1_kernel(const float* __restrict__ m1,
                              const float* __restrict__ m2,
                              const float* __restrict__ m3,
                              const float* __restrict__ W,
                              float* __restrict__ ws) {
    if (blockIdx.x < NPART) {
        __shared__ float sm[4];
        const f32x4* W4 = (const f32x4*)W;
        const unsigned n4 = (DD * DD * DD) / 4;  // 4194304
        float s = 0.f;
        for (unsigned i = blockIdx.x * blockDim.x + threadIdx.x; i < n4; i += NPART * 256) {
            f32x4 v = W4[i];
            s += (v.x + v.y) + (v.z + v.w);
        }
        #pragma unroll
        for (int off = 32; off; off >>= 1) s += __shfl_down(s, off, 64);
        int lane = threadIdx.x & 63, w = threadIdx.x >> 6;
        if (lane == 0) sm[w] = s;
        __syncthreads();
        if (threadIdx.x == 0) ws[WS_PART + blockIdx.x] = (sm[0] + sm[1]) + (sm[2] + sm[3]);
    } else {
        int wave = (int)(blockIdx.x - NPART) * 4 + (int)(threadIdx.x >> 6);
        int lane = threadIdx.x & 63;
        if (wave >= 3 * BB * SS) return;
        const float* src;
        float* dst;
        if (wave < BB * SS)          { src = m1 + (size_t)wave * DD;                 dst = ws + WS_M1 + wave; }
        else if (wave < 2 * BB * SS) { src = m2 + (size_t)(wave - BB * SS) * DD;     dst = ws + WS_M2 + (wave - BB * SS); }
        else                         { src = m3 + (size_t)(wave - 2 * BB * SS) * DD; dst = ws + WS_M3 + (wave - 2 * BB * SS); }
        f32x4 v = ((const f32x4*)src)[lane];
        float s = (v.x + v.y) + (v.z + v.w);
        #pragma unroll
        for (int off = 32; off; off >>= 1) s += __shfl_down(s, off, 64);
        if (lane == 0) *dst = s;
    }
}

// --- V1: slab-per-block writer, NORMAL cached stores (A/B vs R7's measured NT=4.8 TB/s)
__global__ void __launch_bounds__(384) writer_slab_kernel(const float* __restrict__ ws,
                                                          float* __restrict__ out) {
    __shared__ float sred[8];
    __shared__ float m2l[SS];
    int t  = threadIdx.x;
    int bi = blockIdx.x;
    int b  = bi >= SS ? 1 : 0;

    m2l[t] = ws[WS_M2 + b * SS + t];
    float r1 = ws[WS_M1 + bi];
    int jrow = t / 96;
    int k4   = t - jrow * 96;
    f32x4 f = ((const f32x4*)(ws + WS_M3 + b * SS))[k4];

    const float* p = ws + WS_PART;
    float s = p[t] + p[t + 384] + (t < 256 ? p[t + 768] : 0.f);
    #pragma unroll
    for (int off = 32; off; off >>= 1) s += __shfl_down(s, off, 64);
    int lane = t & 63, w = t >> 6;
    if (lane == 0) sred[w] = s;
    __syncthreads();
    if (t == 0) {
        float tot = ((sred[0] + sred[1]) + (sred[2] + sred[3])) + (sred[4] + sred[5]);
        sred[6] = tot * (1.0f / 16.0f);  // SCALE = sqrt(768/3) = 16
    }
    __syncthreads();
    float c1 = r1 * sred[6];

    int k0 = k4 * 4;
    f32x4* dst = (f32x4*)out + (size_t)bi * (SS * SS / 4);
    for (int rep = 0; rep < REPS; ++rep) {
        #pragma unroll 4
        for (int j = jrow; j < SS; j += 4) {
            float cj = c1 * m2l[j];
            f32x4 o;
            o.x = (k0 + 0 > j) ? cj * f.x : 0.f;
            o.y = (k0 + 1 > j) ? cj * f.y : 0.f;
            o.z = (k0 + 2 > j) ? cj * f.z : 0.f;
            o.w = (k0 + 3 > j) ? cj * f.w : 0.f;
            dst[j * 96 + k4] = o;               // plain cached store
        }
        asm volatile("" ::: "memory");
    }
}

// --- V2: lockstep grid-sweep writer. 288 blocks x 256 thr = 73728 threads
// = exactly 2 (j,k)-slabs. Thread owns fixed (slab_off -> j,k4); loop walks bi
// by 2, so the whole grid writes ONE contiguous 1.125MB frontier per iteration
// (fill-like channel distribution). Inner body: ds_read(c1) + 2 mul + store.
__global__ void __launch_bounds__(256) writer_sweep_kernel(const float* __restrict__ ws,
                                                           float* __restrict__ out) {
    __shared__ float sred[8];
    __shared__ float c1l[BB * SS];
    int t = threadIdx.x;

    // block-reduce the 1024 W-partials (deterministic fixed order)
    const float* p = ws + WS_PART;
    float s = (p[t] + p[t + 256]) + (p[t + 512] + p[t + 768]);
    #pragma unroll
    for (int off = 32; off; off >>= 1) s += __shfl_down(s, off, 64);
    int lane = t & 63, w = t >> 6;
    if (lane == 0) sred[w] = s;
    __syncthreads();
    if (t == 0) sred[4] = (((sred[0] + sred[1]) + (sred[2] + sred[3]))) * (1.0f / 16.0f);
    __syncthreads();
    float wt16 = sred[4];

    // stage m1 row sums to LDS (768 floats)
    c1l[t] = ws[WS_M1 + t];
    c1l[t + 256] = ws[WS_M1 + t + 256];
    c1l[t + 512] = ws[WS_M1 + t + 512];

    unsigned g = blockIdx.x * 256u + t;          // 0..73727
    unsigned which = g / (SS * SS / 4);          // 0 or 1
    unsigned so    = g - which * (SS * SS / 4);  // slab offset in float4
    int j  = (int)(so / 96);
    int k4 = (int)(so - (unsigned)j * 96);
    int k0 = k4 * 4;

    // premasked, prescaled f vectors for b=0 and b=1 (j,k fixed per thread)
    f32x4 fa = ((const f32x4*)(ws + WS_M3))[k4];
    f32x4 fb = ((const f32x4*)(ws + WS_M3 + SS))[k4];
    f32x4 fm0, fm1;
    fm0.x = (k0 + 0 > j) ? wt16 * fa.x : 0.f;
    fm0.y = (k0 + 1 > j) ? wt16 * fa.y : 0.f;
    fm0.z = (k0 + 2 > j) ? wt16 * fa.z : 0.f;
    fm0.w = (k0 + 3 > j) ? wt16 * fa.w : 0.f;
    fm1.x = (k0 + 0 > j) ? wt16 * fb.x : 0.f;
    fm1.y = (k0 + 1 > j) ? wt16 * fb.y : 0.f;
    fm1.z = (k0 + 2 > j) ? wt16 * fb.z : 0.f;
    fm1.w = (k0 + 3 > j) ? wt16 * fb.w : 0.f;
    float m2v0 = ws[WS_M2 + j];
    float m2v1 = ws[WS_M2 + SS + j];
    __syncthreads();

    f32x4* base = (f32x4*)out + so;
    for (int rep = 0; rep < REPS; ++rep) {
        f32x4* dst = base + (size_t)which * (SS * SS / 4);
        for (int bi = (int)which; bi < BB * SS; bi += 2) {
            float cj = c1l[bi] * (bi < SS ? m2v0 : m2v1);
            f32x4 fm = (bi < SS) ? fm0 : fm1;
            f32x4 o;
            o.x = cj * fm.x; o.y = cj * fm.y; o.z = cj * fm.z; o.w = cj * fm.w;
            *dst = o;
            dst += 2 * (SS * SS / 4);
        }
        asm volatile("" ::: "memory");
    }
}

extern "C" void kernel_launch(void* const* d_in, const int* in_sizes, int n_in,
                              void* d_out, int out_size, void* d_ws, size_t ws_size,
                              hipStream_t stream) {
    const float* m1 = (const float*)d_in[0];
    const float* m2 = (const float*)d_in[1];
    const float* m3 = (const float*)d_in[2];
    const float* W  = (const float*)d_in[3];
    float* out = (float*)d_out;
    float* ws  = (float*)d_ws;

    stage1_kernel<<<NPART + 576, 256, 0, stream>>>(m1, m2, m3, W, ws);
    // V1: slab writer, normal stores (REPS=5, measured via its own rocprof row)
    writer_slab_kernel<<<BB * SS, 384, 0, stream>>>(ws, out);
    // V2: lockstep frontier writer, normal stores (REPS=5; writes same values)
    writer_sweep_kernel<<<288, 256, 0, stream>>>(ws, out);
}

// Round 9
// 107.864 us; speedup vs baseline: 6.5911x; 6.5911x over previous
//
#include <hip/hip_runtime.h>

#define SS 384
#define BB 2
#define DD 256
#define NPART 1024

typedef float f32x4 __attribute__((ext_vector_type(4)));

// ws float layout:
//  [16..16+1024)  W partial sums
//  [2048..2816)   m1 row sums  (b*S+i)
//  [2816..3584)   m2 row sums
//  [3584..4352)   m3 row sums (raw)
#define WS_PART 16
#define WS_M1 2048
#define WS_M2 2816
#define WS_M3 3584

// --- fused stage 1: blocks [0,NPART) do W partial sums; blocks [NPART, NPART+576) do row sums
__global__ void stage1_kernel(const float* __restrict__ m1,
                              const float* __restrict__ m2,
                              const float* __restrict__ m3,
                              const float* __restrict__ W,
                              float* __restrict__ ws) {
    if (blockIdx.x < NPART) {
        __shared__ float sm[4];
        const f32x4* W4 = (const f32x4*)W;
        const unsigned n4 = (DD * DD * DD) / 4;  // 4194304
        float s = 0.f;
        for (unsigned i = blockIdx.x * blockDim.x + threadIdx.x; i < n4; i += NPART * 256) {
            f32x4 v = W4[i];
            s += (v.x + v.y) + (v.z + v.w);
        }
        #pragma unroll
        for (int off = 32; off; off >>= 1) s += __shfl_down(s, off, 64);
        int lane = threadIdx.x & 63, w = threadIdx.x >> 6;
        if (lane == 0) sm[w] = s;
        __syncthreads();
        if (threadIdx.x == 0) ws[WS_PART + blockIdx.x] = (sm[0] + sm[1]) + (sm[2] + sm[3]);
    } else {
        // row sums: one wave per row, D=256 -> float4/lane
        int wave = (int)(blockIdx.x - NPART) * 4 + (int)(threadIdx.x >> 6);
        int lane = threadIdx.x & 63;
        if (wave >= 3 * BB * SS) return;
        const float* src;
        float* dst;
        if (wave < BB * SS)          { src = m1 + (size_t)wave * DD;                 dst = ws + WS_M1 + wave; }
        else if (wave < 2 * BB * SS) { src = m2 + (size_t)(wave - BB * SS) * DD;     dst = ws + WS_M2 + (wave - BB * SS); }
        else                         { src = m3 + (size_t)(wave - 2 * BB * SS) * DD; dst = ws + WS_M3 + (wave - 2 * BB * SS); }
        f32x4 v = ((const f32x4*)src)[lane];
        float s = (v.x + v.y) + (v.z + v.w);
        #pragma unroll
        for (int off = 32; off; off >>= 1) s += __shfl_down(s, off, 64);
        if (lane == 0) *dst = s;
    }
}

// --- writer: one block per (b,i) slab; 384 threads; PLAIN CACHED stores.
// Measured (R8 A/B): cached slab = ~7.5 TB/s vs NT slab = 4.8, sweep = 5.6.
// Requirements for the fast path: (a) zero vmem loads inside the store loop
// (vmcnt counts loads+stores in order — an in-loop load drains the store
// stream: 4.7 TB/s), (b) normal cached stores (nt forfeits L2 write
// aggregation: 4.8 TB/s).
__global__ void __launch_bounds__(384) writer_kernel(const float* __restrict__ ws,
                                                     float* __restrict__ out) {
    __shared__ float sred[8];
    __shared__ float m2l[SS];
    int t  = threadIdx.x;
    int bi = blockIdx.x;                 // b*S + i
    int b  = bi >= SS ? 1 : 0;

    // --- prologue: ALL vmem loads happen here ---
    m2l[t] = ws[WS_M2 + b * SS + t];               // stage m2 row sums to LDS
    float r1 = ws[WS_M1 + bi];                     // m1 row sum (reg)
    int jrow = t / 96;                             // 0..3
    int k4   = t - jrow * 96;                      // 0..95
    f32x4 f = ((const f32x4*)(ws + WS_M3 + b * SS))[k4];  // m3 row sums (regs)

    // block-wide reduce of the 1024 W-partials (deterministic fixed order)
    const float* p = ws + WS_PART;
    float s = p[t] + p[t + 384] + (t < 256 ? p[t + 768] : 0.f);
    #pragma unroll
    for (int off = 32; off; off >>= 1) s += __shfl_down(s, off, 64);
    int lane = t & 63, w = t >> 6;
    if (lane == 0) sred[w] = s;
    __syncthreads();
    if (t == 0) {
        float tot = ((sred[0] + sred[1]) + (sred[2] + sred[3])) + (sred[4] + sred[5]);
        sred[6] = tot * (1.0f / 16.0f);  // SCALE = sqrt(768/3) = 16
    }
    __syncthreads();
    float c1 = r1 * sred[6];

    // --- store loop: ds_read + VALU + cached store only ---
    int k0 = k4 * 4;
    f32x4* dst = (f32x4*)out + (size_t)bi * (SS * SS / 4);
    #pragma unroll 4
    for (int j = jrow; j < SS; j += 4) {
        float cj = c1 * m2l[j];
        f32x4 o;
        o.x = (k0 + 0 > j) ? cj * f.x : 0.f;
        o.y = (k0 + 1 > j) ? cj * f.y : 0.f;
        o.z = (k0 + 2 > j) ? cj * f.z : 0.f;
        o.w = (k0 + 3 > j) ? cj * f.w : 0.f;
        dst[j * 96 + k4] = o;            // plain cached store — fast path
    }
}

extern "C" void kernel_launch(void* const* d_in, const int* in_sizes, int n_in,
                              void* d_out, int out_size, void* d_ws, size_t ws_size,
                              hipStream_t stream) {
    const float* m1 = (const float*)d_in[0];
    const float* m2 = (const float*)d_in[1];
    const float* m3 = (const float*)d_in[2];
    const float* W  = (const float*)d_in[3];
    float* out = (float*)d_out;
    float* ws  = (float*)d_ws;

    // fused: W partial sums (1024 blocks) + all row sums (576 blocks)
    stage1_kernel<<<NPART + 576, 256, 0, stream>>>(m1, m2, m3, W, ws);
    // masked outer-product write (443 MB), one block per (b,i)
    writer_kernel<<<BB * SS, 384, 0, stream>>>(ws, out);
}

// Round 10
// 103.621 us; speedup vs baseline: 6.8609x; 1.0409x over previous
//
#include <hip/hip_runtime.h>

#define SS 384
#define BB 2
#define DD 256
#define NPART 1024
#define SLAB4 (SS * SS / 4)   // 36864 float4 per (b,i) slab

typedef float f32x4 __attribute__((ext_vector_type(4)));

// ws float layout:
//  [16..16+1024)  W partial sums
//  [2048..2816)   m1 row sums  (b*S+i)
//  [2816..3584)   m2 row sums
//  [3584..4352)   m3 row sums (raw)
#define WS_PART 16
#define WS_M1 2048
#define WS_M2 2816
#define WS_M3 3584

// --- fused stage 1: blocks [0,NPART) do W partial sums; blocks [NPART, NPART+576) do row sums
__global__ void stage1_kernel(const float* __restrict__ m1,
                              const float* __restrict__ m2,
                              const float* __restrict__ m3,
                              const float* __restrict__ W,
                              float* __restrict__ ws) {
    if (blockIdx.x < NPART) {
        __shared__ float sm[4];
        const f32x4* W4 = (const f32x4*)W;
        const unsigned n4 = (DD * DD * DD) / 4;  // 4194304
        float s = 0.f;
        for (unsigned i = blockIdx.x * blockDim.x + threadIdx.x; i < n4; i += NPART * 256) {
            f32x4 v = W4[i];
            s += (v.x + v.y) + (v.z + v.w);
        }
        #pragma unroll
        for (int off = 32; off; off >>= 1) s += __shfl_down(s, off, 64);
        int lane = threadIdx.x & 63, w = threadIdx.x >> 6;
        if (lane == 0) sm[w] = s;
        __syncthreads();
        if (threadIdx.x == 0) ws[WS_PART + blockIdx.x] = (sm[0] + sm[1]) + (sm[2] + sm[3]);
    } else {
        // row sums: one wave per row, D=256 -> float4/lane
        int wave = (int)(blockIdx.x - NPART) * 4 + (int)(threadIdx.x >> 6);
        int lane = threadIdx.x & 63;
        if (wave >= 3 * BB * SS) return;
        const float* src;
        float* dst;
        if (wave < BB * SS)          { src = m1 + (size_t)wave * DD;                 dst = ws + WS_M1 + wave; }
        else if (wave < 2 * BB * SS) { src = m2 + (size_t)(wave - BB * SS) * DD;     dst = ws + WS_M2 + (wave - BB * SS); }
        else                         { src = m3 + (size_t)(wave - 2 * BB * SS) * DD; dst = ws + WS_M3 + (wave - 2 * BB * SS); }
        f32x4 v = ((const f32x4*)src)[lane];
        float s = (v.x + v.y) + (v.z + v.w);
        #pragma unroll
        for (int off = 32; off; off >>= 1) s += __shfl_down(s, off, 64);
        if (lane == 0) *dst = s;
    }
}

// --- writer: lockstep-sweep geometry at HIGH occupancy.
// 1152 blocks x 256 thr = 294912 threads = 8 slabs; each thread owns a fixed
// (j,k4) slot in one of 8 slab positions and walks bi += 8 (96 steps), so the
// whole grid advances ONE contiguous 4.5MB frontier per step (fill-like).
// Measured history: slab@NT 4.78, slab@cached ~5.0, sweep@cached/10%occ 5.57,
// fill 6.9-7.1 TB/s. This raises the sweep's occupancy 4x (18 waves/CU).
// Loop body: ds_read(broadcast) + 5 mul + cached global_store_dwordx4.
// Loop is split at the b boundary so m2/f constants need no per-iter select.
__global__ void __launch_bounds__(256) writer_kernel(const float* __restrict__ ws,
                                                     float* __restrict__ out) {
    __shared__ float sred[8];
    __shared__ float c1l[BB * SS];    // m1 row sums * Wtot/16
    int t = threadIdx.x;

    // block-reduce the 1024 W-partials (deterministic fixed order)
    const float* p = ws + WS_PART;
    float s = (p[t] + p[t + 256]) + (p[t + 512] + p[t + 768]);
    #pragma unroll
    for (int off = 32; off; off >>= 1) s += __shfl_down(s, off, 64);
    int lane = t & 63, w = t >> 6;
    if (lane == 0) sred[w] = s;
    __syncthreads();
    if (t == 0) sred[4] = (((sred[0] + sred[1]) + (sred[2] + sred[3]))) * (1.0f / 16.0f);
    __syncthreads();
    float wt16 = sred[4];             // Wtot / SCALE, SCALE = sqrt(768/3) = 16

    // stage scaled m1 row sums to LDS
    c1l[t]       = ws[WS_M1 + t]       * wt16;
    c1l[t + 256] = ws[WS_M1 + t + 256] * wt16;
    c1l[t + 512] = ws[WS_M1 + t + 512] * wt16;

    unsigned g     = blockIdx.x * 256u + t;   // 0..294911
    unsigned which = g / SLAB4;               // 0..7 (slab position in frontier)
    unsigned so    = g - which * SLAB4;       // slot in slab (float4)
    int j  = (int)(so / 96);
    int k4 = (int)(so - (unsigned)j * 96);
    int k0 = k4 * 4;

    // per-thread constants (prologue vmem loads only)
    f32x4 fa = ((const f32x4*)(ws + WS_M3))[k4];        // b=0 m3 sums
    f32x4 fb = ((const f32x4*)(ws + WS_M3 + SS))[k4];   // b=1
    f32x4 fm0, fm1;
    fm0.x = (k0 + 0 > j) ? fa.x : 0.f;
    fm0.y = (k0 + 1 > j) ? fa.y : 0.f;
    fm0.z = (k0 + 2 > j) ? fa.z : 0.f;
    fm0.w = (k0 + 3 > j) ? fa.w : 0.f;
    fm1.x = (k0 + 0 > j) ? fb.x : 0.f;
    fm1.y = (k0 + 1 > j) ? fb.y : 0.f;
    fm1.z = (k0 + 2 > j) ? fb.z : 0.f;
    fm1.w = (k0 + 3 > j) ? fb.w : 0.f;
    float m2v0 = ws[WS_M2 + j];
    float m2v1 = ws[WS_M2 + SS + j];
    __syncthreads();

    // store loops: no vmem loads inside; cached stores; frontier advances by
    // 8 slabs (4.5MB) per step.
    f32x4* dst = (f32x4*)out + so + (size_t)which * SLAB4;
    int bi = (int)which;
    #pragma unroll 4
    for (; bi < SS; bi += 8) {                 // b = 0 half
        float cj = c1l[bi] * m2v0;
        f32x4 o;
        o.x = cj * fm0.x; o.y = cj * fm0.y; o.z = cj * fm0.z; o.w = cj * fm0.w;
        *dst = o;
        dst += 8 * SLAB4;
    }
    #pragma unroll 4
    for (; bi < BB * SS; bi += 8) {            // b = 1 half
        float cj = c1l[bi] * m2v1;
        f32x4 o;
        o.x = cj * fm1.x; o.y = cj * fm1.y; o.z = cj * fm1.z; o.w = cj * fm1.w;
        *dst = o;
        dst += 8 * SLAB4;
    }
}

extern "C" void kernel_launch(void* const* d_in, const int* in_sizes, int n_in,
                              void* d_out, int out_size, void* d_ws, size_t ws_size,
                              hipStream_t stream) {
    const float* m1 = (const float*)d_in[0];
    const float* m2 = (const float*)d_in[1];
    const float* m3 = (const float*)d_in[2];
    const float* W  = (const float*)d_in[3];
    float* out = (float*)d_out;
    float* ws  = (float*)d_ws;

    // fused: W partial sums (1024 blocks) + all row sums (576 blocks)
    stage1_kernel<<<NPART + 576, 256, 0, stream>>>(m1, m2, m3, W, ws);
    // masked outer-product write (443 MB), high-occupancy lockstep sweep
    writer_kernel<<<1152, 256, 0, stream>>>(ws, out);
}

// Round 11
// 102.329 us; speedup vs baseline: 6.9476x; 1.0126x over previous
//
#include <hip/hip_runtime.h>

#define SS 384
#define BB 2
#define DD 256
#define NPART 1024
#define SLAB4 (SS * SS / 4)   // 36864 float4 per (b,i) slab

typedef float f32x4 __attribute__((ext_vector_type(4)));

// ws float layout:
//  [16..16+1024)  W partial sums
//  [2048..2816)   m1 row sums  (b*S+i)
//  [2816..3584)   m2 row sums
//  [3584..4352)   m3 row sums (raw)
#define WS_PART 16
#define WS_M1 2048
#define WS_M2 2816
#define WS_M3 3584

// --- fused stage 1: blocks [0,NPART) do W partial sums; blocks [NPART, NPART+576) do row sums
__global__ void stage1_kernel(const float* __restrict__ m1,
                              const float* __restrict__ m2,
                              const float* __restrict__ m3,
                              const float* __restrict__ W,
                              float* __restrict__ ws) {
    if (blockIdx.x < NPART) {
        __shared__ float sm[4];
        const f32x4* W4 = (const f32x4*)W;
        const unsigned n4 = (DD * DD * DD) / 4;  // 4194304
        float s = 0.f;
        for (unsigned i = blockIdx.x * blockDim.x + threadIdx.x; i < n4; i += NPART * 256) {
            f32x4 v = W4[i];
            s += (v.x + v.y) + (v.z + v.w);
        }
        #pragma unroll
        for (int off = 32; off; off >>= 1) s += __shfl_down(s, off, 64);
        int lane = threadIdx.x & 63, w = threadIdx.x >> 6;
        if (lane == 0) sm[w] = s;
        __syncthreads();
        if (threadIdx.x == 0) ws[WS_PART + blockIdx.x] = (sm[0] + sm[1]) + (sm[2] + sm[3]);
    } else {
        // row sums: one wave per row, D=256 -> float4/lane
        int wave = (int)(blockIdx.x - NPART) * 4 + (int)(threadIdx.x >> 6);
        int lane = threadIdx.x & 63;
        if (wave >= 3 * BB * SS) return;
        const float* src;
        float* dst;
        if (wave < BB * SS)          { src = m1 + (size_t)wave * DD;                 dst = ws + WS_M1 + wave; }
        else if (wave < 2 * BB * SS) { src = m2 + (size_t)(wave - BB * SS) * DD;     dst = ws + WS_M2 + (wave - BB * SS); }
        else                         { src = m3 + (size_t)(wave - 2 * BB * SS) * DD; dst = ws + WS_M3 + (wave - 2 * BB * SS); }
        f32x4 v = ((const f32x4*)src)[lane];
        float s = (v.x + v.y) + (v.z + v.w);
        #pragma unroll
        for (int off = 32; off; off >>= 1) s += __shfl_down(s, off, 64);
        if (lane == 0) *dst = s;
    }
}

// --- writer: lockstep sweep + register-staged store bursts.
// 1152 blocks x 256 thr = 294912 threads = 8 slabs of frontier; thread owns a
// fixed (j,k4) slot, walks bi += 8 (96 steps). The 96 steps are processed in
// 6 chunks of 16: phase A = 16 broadcast ds_reads -> cj regs (static unroll),
// phase B = 16 dependency-free cached global_store_dwordx4 back-to-back.
// Rationale (R8/R10 measured): in-loop per-store ds_read dependency left waves
// 88% idle at 5.0-5.6 TB/s; fill (no store-input deps) runs 6.9-7.1.
__global__ void __launch_bounds__(256) writer_kernel(const float* __restrict__ ws,
                                                     float* __restrict__ out) {
    __shared__ float sred[8];
    __shared__ float c1l[BB * SS];    // m1 row sums * Wtot/16
    int t = threadIdx.x;

    // block-reduce the 1024 W-partials (deterministic fixed order)
    const float* p = ws + WS_PART;
    float s = (p[t] + p[t + 256]) + (p[t + 512] + p[t + 768]);
    #pragma unroll
    for (int off = 32; off; off >>= 1) s += __shfl_down(s, off, 64);
    int lane = t & 63, w = t >> 6;
    if (lane == 0) sred[w] = s;
    __syncthreads();
    if (t == 0) sred[4] = (((sred[0] + sred[1]) + (sred[2] + sred[3]))) * (1.0f / 16.0f);
    __syncthreads();
    float wt16 = sred[4];             // Wtot / SCALE, SCALE = sqrt(768/3) = 16

    // stage scaled m1 row sums to LDS
    c1l[t]       = ws[WS_M1 + t]       * wt16;
    c1l[t + 256] = ws[WS_M1 + t + 256] * wt16;
    c1l[t + 512] = ws[WS_M1 + t + 512] * wt16;

    unsigned g     = blockIdx.x * 256u + t;   // 0..294911
    unsigned which = g / SLAB4;               // 0..7 (slab position in frontier)
    unsigned so    = g - which * SLAB4;       // slot in slab (float4)
    int j  = (int)(so / 96);
    int k4 = (int)(so - (unsigned)j * 96);
    int k0 = k4 * 4;

    // per-thread constants (prologue vmem loads only)
    f32x4 fa = ((const f32x4*)(ws + WS_M3))[k4];        // b=0 m3 sums
    f32x4 fb = ((const f32x4*)(ws + WS_M3 + SS))[k4];   // b=1
    f32x4 fm0, fm1;
    fm0.x = (k0 + 0 > j) ? fa.x : 0.f;
    fm0.y = (k0 + 1 > j) ? fa.y : 0.f;
    fm0.z = (k0 + 2 > j) ? fa.z : 0.f;
    fm0.w = (k0 + 3 > j) ? fa.w : 0.f;
    fm1.x = (k0 + 0 > j) ? fb.x : 0.f;
    fm1.y = (k0 + 1 > j) ? fb.y : 0.f;
    fm1.z = (k0 + 2 > j) ? fb.z : 0.f;
    fm1.w = (k0 + 3 > j) ? fb.w : 0.f;
    float m2v0 = ws[WS_M2 + j];
    float m2v1 = ws[WS_M2 + SS + j];
    __syncthreads();

    // fully-static chunked store loop: 6 chunks x {16 ds_reads -> 16 stores}
    const float* c1p = c1l + which;           // bi = which + step*8
    f32x4* dst = (f32x4*)out + so + (size_t)which * SLAB4;
    #pragma unroll
    for (int ch = 0; ch < 6; ++ch) {
        float m2v = (ch < 3) ? m2v0 : m2v1;   // b boundary at step 48 (chunk 3)
        f32x4 fm  = (ch < 3) ? fm0 : fm1;
        float cj[16];
        #pragma unroll
        for (int q = 0; q < 16; ++q)
            cj[q] = c1p[(ch * 16 + q) * 8] * m2v;   // broadcast ds_read, static offset
        #pragma unroll
        for (int q = 0; q < 16; ++q) {
            f32x4 o;
            o.x = cj[q] * fm.x;
            o.y = cj[q] * fm.y;
            o.z = cj[q] * fm.z;
            o.w = cj[q] * fm.w;
            dst[(size_t)(ch * 16 + q) * 8 * SLAB4] = o;  // dependency-free burst
        }
    }
}

extern "C" void kernel_launch(void* const* d_in, const int* in_sizes, int n_in,
                              void* d_out, int out_size, void* d_ws, size_t ws_size,
                              hipStream_t stream) {
    const float* m1 = (const float*)d_in[0];
    const float* m2 = (const float*)d_in[1];
    const float* m3 = (const float*)d_in[2];
    const float* W  = (const float*)d_in[3];
    float* out = (float*)d_out;
    float* ws  = (float*)d_ws;

    // fused: W partial sums (1024 blocks) + all row sums (576 blocks)
    stage1_kernel<<<NPART + 576, 256, 0, stream>>>(m1, m2, m3, W, ws);
    // masked outer-product write (443 MB), register-staged store bursts
    writer_kernel<<<1152, 256, 0, stream>>>(ws, out);
}